// Round 1
// baseline (11767.144 us; speedup 1.0000x reference)
//
#include <hip/hip_runtime.h>

typedef _Float16 f16;
typedef _Float16 f16x8 __attribute__((ext_vector_type(8)));
typedef float    f32x4 __attribute__((ext_vector_type(4)));

#define TSEQ 128
#define PRED 10

// ---------------- small utility kernels ----------------
__global__ void k_cvt(const float* __restrict__ src, f16* __restrict__ dst, int n) {
  int i = blockIdx.x * blockDim.x + threadIdx.x;
  int stride = gridDim.x * blockDim.x;
  for (; i < n; i += stride) dst[i] = (f16)src[i];
}

__global__ void k_bias(const float* __restrict__ a, const float* __restrict__ b,
                       float* __restrict__ o, int n) {
  int i = blockIdx.x * blockDim.x + threadIdx.x;
  if (i < n) o[i] = a[i] + b[i];
}

// ---------------- input-transform GEMM ----------------
// C[M,512](f16) = A[M,512](f16) @ W[512,512]^T (W row-major [n][k]) + bias[n]
// BM=128, BN=256, BK=64; 256 threads = 4 waves in 2x2; wave tile 64x128.
__global__ __launch_bounds__(256) void k_gemm_xw(
    const f16* __restrict__ A, const f16* __restrict__ W,
    const float* __restrict__ bias, f16* __restrict__ C) {
  __shared__ f16 As[128 * 72];
  __shared__ f16 Bs[256 * 72];
  const int tid = threadIdx.x;
  const int w = tid >> 6, lane = tid & 63;
  const int wm = w >> 1, wn = w & 1;
  const int q = lane >> 4, l15 = lane & 15;
  const int m0 = blockIdx.x * 128;
  const int n0 = blockIdx.y * 256;

  f32x4 acc[4][8];
  const f32x4 zero = {0.f, 0.f, 0.f, 0.f};
#pragma unroll
  for (int i = 0; i < 4; i++)
#pragma unroll
    for (int j = 0; j < 8; j++) acc[i][j] = zero;

  for (int k0 = 0; k0 < 512; k0 += 64) {
    __syncthreads();
#pragma unroll
    for (int i = 0; i < 4; i++) {
      int ch = tid + 256 * i; int r = ch >> 3, kc = ch & 7;
      *(f16x8*)&As[r * 72 + kc * 8] = *(const f16x8*)&A[(size_t)(m0 + r) * 512 + k0 + kc * 8];
    }
#pragma unroll
    for (int i = 0; i < 8; i++) {
      int ch = tid + 256 * i; int r = ch >> 3, kc = ch & 7;
      *(f16x8*)&Bs[r * 72 + kc * 8] = *(const f16x8*)&W[(size_t)(n0 + r) * 512 + k0 + kc * 8];
    }
    __syncthreads();
#pragma unroll
    for (int kk = 0; kk < 2; kk++) {
      f16x8 af[4], bf[8];
#pragma unroll
      for (int mt = 0; mt < 4; mt++)
        af[mt] = *(const f16x8*)&As[(wm * 64 + mt * 16 + l15) * 72 + kk * 32 + q * 8];
#pragma unroll
      for (int nt = 0; nt < 8; nt++)
        bf[nt] = *(const f16x8*)&Bs[(wn * 128 + nt * 16 + l15) * 72 + kk * 32 + q * 8];
#pragma unroll
      for (int mt = 0; mt < 4; mt++)
#pragma unroll
        for (int nt = 0; nt < 8; nt++)
          acc[mt][nt] = __builtin_amdgcn_mfma_f32_16x16x32_f16(af[mt], bf[nt], acc[mt][nt], 0, 0, 0);
    }
  }
#pragma unroll
  for (int mt = 0; mt < 4; mt++)
#pragma unroll
    for (int nt = 0; nt < 8; nt++)
#pragma unroll
      for (int r = 0; r < 4; r++) {
        int mg = m0 + wm * 64 + mt * 16 + q * 4 + r;
        int ng = n0 + wn * 128 + nt * 16 + l15;
        C[(size_t)mg * 512 + ng] = (f16)(acc[mt][nt][r] + bias[ng]);
      }
}

// ---------------- encoder recurrence (cluster of 4 blocks) ----------------
// grid 256: cluster c = blockIdx&63 owns batch rows [16c,16c+16); sub = blockIdx>>6
// owns output cols [128*sub, 128*sub+128). Whh fragments register-resident.
__global__ __launch_bounds__(256) void k_enc_rec(
    const f16* __restrict__ xw, const float* __restrict__ x,
    const float* __restrict__ Wih0, const float* __restrict__ bias0,
    const f16* __restrict__ Whh, f16* __restrict__ out_h,
    float* __restrict__ out_f, f16* __restrict__ hT,
    int* __restrict__ ctr, int is_l0) {
  __shared__ f16 As[16 * 520];
  __shared__ float xs[16][8];
  const int tid = threadIdx.x;
  const int w = tid >> 6, lane = tid & 63, q = lane >> 4, l15 = lane & 15;
  const int c = blockIdx.x & 63, sub = blockIdx.x >> 6;
  const int row0 = c * 16;
  const int ncol0 = sub * 128 + w * 32;
  int* myctr = ctr + c * 32;

  // resident B fragments: Whh[n][k], lane holds B[k][n] with n=l15, k=q*8..q*8+8
  f16x8 Bfr[2][16];
#pragma unroll
  for (int t2 = 0; t2 < 2; t2++) {
    int ng = ncol0 + t2 * 16 + l15;
#pragma unroll
    for (int kk = 0; kk < 16; kk++)
      Bfr[t2][kk] = *(const f16x8*)&Whh[(size_t)ng * 512 + kk * 32 + q * 8];
  }

  float w0[2][6]; float b0[2];
  if (is_l0) {
#pragma unroll
    for (int t2 = 0; t2 < 2; t2++) {
      int ng = ncol0 + t2 * 16 + l15;
#pragma unroll
      for (int d = 0; d < 6; d++) w0[t2][d] = Wih0[ng * 6 + d];
      b0[t2] = bias0[ng];
    }
  }

  for (int i = tid; i < 16 * 520; i += 256) As[i] = (f16)0.0f;
  if (is_l0 && tid < 96) xs[tid / 6][tid % 6] = x[(size_t)(row0 + tid / 6) * TSEQ * 6 + tid % 6];
  __syncthreads();

  for (int t = 0; t < TSEQ; t++) {
    const f32x4 zero = {0.f, 0.f, 0.f, 0.f};
    f32x4 acc0 = zero, acc1 = zero;
#pragma unroll
    for (int kk = 0; kk < 16; kk++) {
      f16x8 a = *(const f16x8*)&As[l15 * 520 + kk * 32 + q * 8];
      acc0 = __builtin_amdgcn_mfma_f32_16x16x32_f16(a, Bfr[0][kk], acc0, 0, 0, 0);
      acc1 = __builtin_amdgcn_mfma_f32_16x16x32_f16(a, Bfr[1][kk], acc1, 0, 0, 0);
    }
#pragma unroll
    for (int t2 = 0; t2 < 2; t2++) {
      f32x4 accv = t2 ? acc1 : acc0;
      int ng = ncol0 + t2 * 16 + l15;
#pragma unroll
      for (int r = 0; r < 4; r++) {
        int m = q * 4 + r;
        int b = row0 + m;
        float pre;
        if (is_l0) {
          float xwv = b0[t2];
#pragma unroll
          for (int d = 0; d < 6; d++) xwv += xs[m][d] * w0[t2][d];
          pre = accv[r] + xwv;
        } else {
          pre = accv[r] + (float)xw[((size_t)b * TSEQ + t) * 512 + ng];
        }
        float h = tanhf(pre);
        out_h[((size_t)b * TSEQ + t) * 512 + ng] = (f16)h;
        if (out_f) out_f[((size_t)b * TSEQ + t) * 512 + ng] = h;
        if (t == TSEQ - 1) hT[(size_t)b * 512 + ng] = (f16)h;
      }
    }
    if (t == TSEQ - 1) break;
    __syncthreads();  // drains each thread's global writes (vmcnt 0) before arrive
    if (tid == 0) {
      __threadfence();  // agent-scope release: L2 writeback for cross-XCD peers
      __hip_atomic_fetch_add(myctr, 1, __ATOMIC_RELEASE, __HIP_MEMORY_SCOPE_AGENT);
      int target = 4 * (t + 1);
      while (__hip_atomic_load(myctr, __ATOMIC_RELAXED, __HIP_MEMORY_SCOPE_AGENT) < target)
        __builtin_amdgcn_s_sleep(1);
      __threadfence();  // acquire: invalidate stale L1/L2 lines
    }
    __syncthreads();
    // rebuild full h_t (16 rows x 512) into LDS from all 4 cluster blocks
#pragma unroll
    for (int i = 0; i < 4; i++) {
      int idx = tid + 256 * i;  // 0..1023 -> 16 rows x 64 chunks
      int m = idx >> 6, kc = idx & 63;
      *(f16x8*)&As[m * 520 + kc * 8] =
          *(const f16x8*)&out_h[((size_t)(row0 + m) * TSEQ + t) * 512 + kc * 8];
    }
    if (is_l0 && tid < 96)
      xs[tid / 6][tid % 6] = x[((size_t)(row0 + tid / 6) * TSEQ + (t + 1)) * 6 + tid % 6];
    __syncthreads();
  }
}

// ---------------- decoder (cluster of 4 blocks, weights streamed) ----------------
__global__ __launch_bounds__(256) void k_dec_rec(
    const f16* __restrict__ Wih, const f16* __restrict__ Whh,
    const float* __restrict__ decB, const f16* __restrict__ hT,
    f16* __restrict__ hstate, f16* __restrict__ dec_out, int* __restrict__ ctr) {
  __shared__ f16 xb[16 * 520];
  __shared__ f16 hb[16 * 520];
  const int tid = threadIdx.x;
  const int w = tid >> 6, lane = tid & 63, q = lane >> 4, l15 = lane & 15;
  const int c = blockIdx.x & 63, sub = blockIdx.x >> 6;
  const int row0 = c * 16;
  const int ncol0 = sub * 128 + w * 32;
  int* myctr = ctr + c * 32;
  const size_t LSZ = (size_t)1024 * 512;

  for (int s = 0; s < PRED; s++) {
    int wb = (s + 1) & 1, rb = s & 1;
    for (int l = 0; l < 4; l++) {
      const f16* xsrc = (l == 0) ? (s == 0 ? hT + 3 * LSZ : hstate + ((size_t)rb * 4 + 3) * LSZ)
                                 : hstate + ((size_t)wb * 4 + (l - 1)) * LSZ;
      const f16* hsrc = (s == 0) ? hT + (size_t)l * LSZ : hstate + ((size_t)rb * 4 + l) * LSZ;
#pragma unroll
      for (int i = 0; i < 4; i++) {
        int idx = tid + 256 * i; int m = idx >> 6, kc = idx & 63;
        *(f16x8*)&xb[m * 520 + kc * 8] = *(const f16x8*)&xsrc[(size_t)(row0 + m) * 512 + kc * 8];
        *(f16x8*)&hb[m * 520 + kc * 8] = *(const f16x8*)&hsrc[(size_t)(row0 + m) * 512 + kc * 8];
      }
      __syncthreads();
      const f32x4 zero = {0.f, 0.f, 0.f, 0.f};
      f32x4 acc0 = zero, acc1 = zero;
      const f16* Wl = Wih + (size_t)l * 512 * 512;
      const f16* Ul = Whh + (size_t)l * 512 * 512;
      int ng0 = ncol0 + l15, ng1 = ncol0 + 16 + l15;
#pragma unroll
      for (int kk = 0; kk < 16; kk++) {
        f16x8 a = *(const f16x8*)&xb[l15 * 520 + kk * 32 + q * 8];
        f16x8 bv0 = *(const f16x8*)&Wl[(size_t)ng0 * 512 + kk * 32 + q * 8];
        f16x8 bv1 = *(const f16x8*)&Wl[(size_t)ng1 * 512 + kk * 32 + q * 8];
        acc0 = __builtin_amdgcn_mfma_f32_16x16x32_f16(a, bv0, acc0, 0, 0, 0);
        acc1 = __builtin_amdgcn_mfma_f32_16x16x32_f16(a, bv1, acc1, 0, 0, 0);
      }
#pragma unroll
      for (int kk = 0; kk < 16; kk++) {
        f16x8 a = *(const f16x8*)&hb[l15 * 520 + kk * 32 + q * 8];
        f16x8 bv0 = *(const f16x8*)&Ul[(size_t)ng0 * 512 + kk * 32 + q * 8];
        f16x8 bv1 = *(const f16x8*)&Ul[(size_t)ng1 * 512 + kk * 32 + q * 8];
        acc0 = __builtin_amdgcn_mfma_f32_16x16x32_f16(a, bv0, acc0, 0, 0, 0);
        acc1 = __builtin_amdgcn_mfma_f32_16x16x32_f16(a, bv1, acc1, 0, 0, 0);
      }
      __syncthreads();  // all waves done reading xb/hb
#pragma unroll
      for (int t2 = 0; t2 < 2; t2++) {
        f32x4 accv = t2 ? acc1 : acc0;
        int ng = ncol0 + t2 * 16 + l15;
#pragma unroll
        for (int r = 0; r < 4; r++) {
          int b = row0 + q * 4 + r;
          float h = tanhf(accv[r] + decB[l * 512 + ng]);
          hstate[((size_t)wb * 4 + l) * LSZ + (size_t)b * 512 + ng] = (f16)h;
          if (l == 3) dec_out[((size_t)b * PRED + s) * 512 + ng] = (f16)h;
        }
      }
      __syncthreads();
      if (tid == 0) {
        __threadfence();
        __hip_atomic_fetch_add(myctr, 1, __ATOMIC_RELEASE, __HIP_MEMORY_SCOPE_AGENT);
        int target = 4 * (s * 4 + l + 1);
        while (__hip_atomic_load(myctr, __ATOMIC_RELAXED, __HIP_MEMORY_SCOPE_AGENT) < target)
          __builtin_amdgcn_s_sleep(1);
        __threadfence();
      }
      __syncthreads();
    }
  }
}

// ---------------- final FC ----------------
__global__ __launch_bounds__(256) void k_fc(
    const f16* __restrict__ dec_out, const float* __restrict__ fcW,
    const float* __restrict__ fcb, float* __restrict__ out) {
  __shared__ float Wl[6 * 512];
  __shared__ float bl[8];
  int tid = threadIdx.x;
  for (int i = tid; i < 3072; i += 256) Wl[i] = fcW[i];
  if (tid < 6) bl[tid] = fcb[tid];
  __syncthreads();
  int g = blockIdx.x * 256 + tid;  // 0..10239
  const f16* row = dec_out + (size_t)g * 512;
  float acc[6] = {0, 0, 0, 0, 0, 0};
  for (int kc = 0; kc < 64; kc++) {
    f16x8 xv = *(const f16x8*)&row[kc * 8];
#pragma unroll
    for (int j = 0; j < 8; j++) {
      float xf = (float)xv[j];
#pragma unroll
      for (int o = 0; o < 6; o++) acc[o] += xf * Wl[o * 512 + kc * 8 + j];
    }
  }
#pragma unroll
  for (int o = 0; o < 6; o++) out[(size_t)g * 6 + o] = acc[o] + bl[o];
}

extern "C" void kernel_launch(void* const* d_in, const int* in_sizes, int n_in,
                              void* d_out, int out_size, void* d_ws, size_t ws_size,
                              hipStream_t stream) {
  const float* x      = (const float*)d_in[0];
  const float* Wih0   = (const float*)d_in[1];
  const float* eWih32 = (const float*)d_in[2];
  const float* eWhh32 = (const float*)d_in[3];
  const float* ebih   = (const float*)d_in[4];
  const float* ebhh   = (const float*)d_in[5];
  const float* dWih32 = (const float*)d_in[6];
  const float* dWhh32 = (const float*)d_in[7];
  const float* dbih   = (const float*)d_in[8];
  const float* dbhh   = (const float*)d_in[9];
  const float* fcW    = (const float*)d_in[10];
  const float* fcb    = (const float*)d_in[11];
  float* outp = (float*)d_out;

  char* ws = (char*)d_ws;
  size_t off = 0;
  auto alloc = [&](size_t bytes) { void* p = ws + off; off += (bytes + 255) & ~255ULL; return p; };
  f16* outA   = (f16*)alloc((size_t)131072 * 512 * 2);
  f16* xwB    = (f16*)alloc((size_t)131072 * 512 * 2);
  f16* eWih   = (f16*)alloc((size_t)3 * 262144 * 2);
  f16* eWhh   = (f16*)alloc((size_t)4 * 262144 * 2);
  f16* dWih   = (f16*)alloc((size_t)4 * 262144 * 2);
  f16* dWhh   = (f16*)alloc((size_t)4 * 262144 * 2);
  float* encB = (float*)alloc(2048 * 4);
  float* decB = (float*)alloc(2048 * 4);
  f16* hT     = (f16*)alloc((size_t)4 * 1024 * 512 * 2);
  f16* hstate = (f16*)alloc((size_t)8 * 1024 * 512 * 2);
  f16* dec_o  = (f16*)alloc((size_t)1024 * 10 * 512 * 2);
  int* ctr    = (int*)alloc(5 * 64 * 32 * 4);

  hipMemsetAsync(ctr, 0, 5 * 64 * 32 * 4, stream);
  k_cvt<<<512, 256, 0, stream>>>(eWih32, eWih, 3 * 262144);
  k_cvt<<<512, 256, 0, stream>>>(eWhh32, eWhh, 4 * 262144);
  k_cvt<<<512, 256, 0, stream>>>(dWih32, dWih, 4 * 262144);
  k_cvt<<<512, 256, 0, stream>>>(dWhh32, dWhh, 4 * 262144);
  k_bias<<<8, 256, 0, stream>>>(ebih, ebhh, encB, 2048);
  k_bias<<<8, 256, 0, stream>>>(dbih, dbhh, decB, 2048);

  // encoder layer 0 (input transform K=6 fused)
  k_enc_rec<<<256, 256, 0, stream>>>(nullptr, x, Wih0, encB, eWhh, outA, nullptr, hT, ctr, 1);
  for (int l = 1; l < 4; l++) {
    k_gemm_xw<<<dim3(1024, 2), 256, 0, stream>>>(outA, eWih + (size_t)(l - 1) * 262144,
                                                 encB + l * 512, xwB);
    float* of = (l == 3) ? outp : nullptr;
    k_enc_rec<<<256, 256, 0, stream>>>(xwB, nullptr, nullptr, nullptr,
                                       eWhh + (size_t)l * 262144, outA, of,
                                       hT + (size_t)l * 524288, ctr + l * 2048, 0);
  }
  k_dec_rec<<<256, 256, 0, stream>>>(dWih, dWhh, decB, hT, hstate, dec_o, ctr + 4 * 2048);
  k_fc<<<40, 256, 0, stream>>>(dec_o, fcW, fcb, outp + (size_t)1024 * 128 * 512);
}

// Round 2
// 3434.459 us; speedup vs baseline: 3.4262x; 3.4262x over previous
//
#include <hip/hip_runtime.h>

typedef _Float16 f16;
typedef _Float16 f16x8 __attribute__((ext_vector_type(8)));
typedef float    f32x4 __attribute__((ext_vector_type(4)));

#define TSEQ 128
#define PRED 10

// ---------------- small utility kernels ----------------
__global__ void k_cvt(const float* __restrict__ src, f16* __restrict__ dst, int n) {
  int i = blockIdx.x * blockDim.x + threadIdx.x;
  int stride = gridDim.x * blockDim.x;
  for (; i < n; i += stride) dst[i] = (f16)src[i];
}

__global__ void k_bias(const float* __restrict__ a, const float* __restrict__ b,
                       float* __restrict__ o, int n) {
  int i = blockIdx.x * blockDim.x + threadIdx.x;
  if (i < n) o[i] = a[i] + b[i];
}

// ---------------- input-transform GEMM ----------------
// C[M,512](f16) = A[M,512](f16) @ W[512,512]^T (W row-major [n][k]) + bias[n]
__global__ __launch_bounds__(256) void k_gemm_xw(
    const f16* __restrict__ A, const f16* __restrict__ W,
    const float* __restrict__ bias, f16* __restrict__ C) {
  __shared__ f16 As[128 * 72];
  __shared__ f16 Bs[256 * 72];
  const int tid = threadIdx.x;
  const int w = tid >> 6, lane = tid & 63;
  const int wm = w >> 1, wn = w & 1;
  const int q = lane >> 4, l15 = lane & 15;
  const int m0 = blockIdx.x * 128;
  const int n0 = blockIdx.y * 256;

  f32x4 acc[4][8];
  const f32x4 zero = {0.f, 0.f, 0.f, 0.f};
#pragma unroll
  for (int i = 0; i < 4; i++)
#pragma unroll
    for (int j = 0; j < 8; j++) acc[i][j] = zero;

  for (int k0 = 0; k0 < 512; k0 += 64) {
    __syncthreads();
#pragma unroll
    for (int i = 0; i < 4; i++) {
      int ch = tid + 256 * i; int r = ch >> 3, kc = ch & 7;
      *(f16x8*)&As[r * 72 + kc * 8] = *(const f16x8*)&A[(size_t)(m0 + r) * 512 + k0 + kc * 8];
    }
#pragma unroll
    for (int i = 0; i < 8; i++) {
      int ch = tid + 256 * i; int r = ch >> 3, kc = ch & 7;
      *(f16x8*)&Bs[r * 72 + kc * 8] = *(const f16x8*)&W[(size_t)(n0 + r) * 512 + k0 + kc * 8];
    }
    __syncthreads();
#pragma unroll
    for (int kk = 0; kk < 2; kk++) {
      f16x8 af[4], bf[8];
#pragma unroll
      for (int mt = 0; mt < 4; mt++)
        af[mt] = *(const f16x8*)&As[(wm * 64 + mt * 16 + l15) * 72 + kk * 32 + q * 8];
#pragma unroll
      for (int nt = 0; nt < 8; nt++)
        bf[nt] = *(const f16x8*)&Bs[(wn * 128 + nt * 16 + l15) * 72 + kk * 32 + q * 8];
#pragma unroll
      for (int mt = 0; mt < 4; mt++)
#pragma unroll
        for (int nt = 0; nt < 8; nt++)
          acc[mt][nt] = __builtin_amdgcn_mfma_f32_16x16x32_f16(af[mt], bf[nt], acc[mt][nt], 0, 0, 0);
    }
  }
#pragma unroll
  for (int mt = 0; mt < 4; mt++)
#pragma unroll
    for (int nt = 0; nt < 8; nt++)
#pragma unroll
      for (int r = 0; r < 4; r++) {
        int mg = m0 + wm * 64 + mt * 16 + q * 4 + r;
        int ng = n0 + wn * 128 + nt * 16 + l15;
        C[(size_t)mg * 512 + ng] = (f16)(acc[mt][nt][r] + bias[ng]);
      }
}

// ---------------- encoder recurrence (cluster of 4 blocks, fence-free sync) ----
// hx exchange layout: [parity 2][cluster 64][col 512][row 16] f16, accessed only
// via relaxed AGENT-scope atomics (sc-flagged, cache-bypassing) — no threadfence.
__global__ __launch_bounds__(256) void k_enc_rec(
    const f16* __restrict__ xw, const float* __restrict__ x,
    const float* __restrict__ Wih0, const float* __restrict__ bias0,
    const f16* __restrict__ Whh, f16* __restrict__ out_h,
    float* __restrict__ out_f, f16* __restrict__ hT,
    f16* __restrict__ hx, int* __restrict__ ctr, int is_l0) {
  __shared__ f16 As[16 * 520];
  __shared__ float xs[16][8];
  const int tid = threadIdx.x;
  const int w = tid >> 6, lane = tid & 63, q = lane >> 4, l15 = lane & 15;
  const int c = blockIdx.x & 63, sub = blockIdx.x >> 6;
  const int row0 = c * 16;
  const int ncol0 = sub * 128 + w * 32;
  int* myctr = ctr + c * 32;

  // register-resident B fragments of Whh for this block's 128 cols
  f16x8 Bfr[2][16];
#pragma unroll
  for (int t2 = 0; t2 < 2; t2++) {
    int ng = ncol0 + t2 * 16 + l15;
#pragma unroll
    for (int kk = 0; kk < 16; kk++)
      Bfr[t2][kk] = *(const f16x8*)&Whh[(size_t)ng * 512 + kk * 32 + q * 8];
  }

  float w0[2][6]; float b0[2];
  if (is_l0) {
#pragma unroll
    for (int t2 = 0; t2 < 2; t2++) {
      int ng = ncol0 + t2 * 16 + l15;
#pragma unroll
      for (int d = 0; d < 6; d++) w0[t2][d] = Wih0[ng * 6 + d];
      b0[t2] = bias0[ng];
    }
  }

  for (int i = tid; i < 16 * 520; i += 256) As[i] = (f16)0.0f;
  if (is_l0 && tid < 96) xs[tid / 6][tid % 6] = x[(size_t)(row0 + tid / 6) * TSEQ * 6 + tid % 6];
  __syncthreads();

  for (int t = 0; t < TSEQ; t++) {
    const int p = t & 1;
    // hoist xw loads (HBM/L3 latency hidden under MFMA)
    f16 xwr[2][4];
    if (!is_l0) {
#pragma unroll
      for (int t2 = 0; t2 < 2; t2++)
#pragma unroll
        for (int r = 0; r < 4; r++)
          xwr[t2][r] = xw[((size_t)(row0 + q * 4 + r) * TSEQ + t) * 512 + ncol0 + t2 * 16 + l15];
    }

    const f32x4 zero = {0.f, 0.f, 0.f, 0.f};
    f32x4 acc0 = zero, acc1 = zero;
#pragma unroll
    for (int kk = 0; kk < 16; kk++) {
      f16x8 a = *(const f16x8*)&As[l15 * 520 + kk * 32 + q * 8];
      acc0 = __builtin_amdgcn_mfma_f32_16x16x32_f16(a, Bfr[0][kk], acc0, 0, 0, 0);
      acc1 = __builtin_amdgcn_mfma_f32_16x16x32_f16(a, Bfr[1][kk], acc1, 0, 0, 0);
    }

#pragma unroll
    for (int t2 = 0; t2 < 2; t2++) {
      f32x4 accv = t2 ? acc1 : acc0;
      int ng = ncol0 + t2 * 16 + l15;
      union { unsigned long long u; f16 h4[4]; } pk;
      float hv[4];
#pragma unroll
      for (int r = 0; r < 4; r++) {
        int m = q * 4 + r;
        float pre;
        if (is_l0) {
          float xwv = b0[t2];
#pragma unroll
          for (int d = 0; d < 6; d++) xwv += xs[m][d] * w0[t2][d];
          pre = accv[r] + xwv;
        } else {
          pre = accv[r] + (float)xwr[t2][r];
        }
        hv[r] = tanhf(pre);
        pk.h4[r] = (f16)hv[r];
      }
      if (t < TSEQ - 1)  // coherent exchange store: 4 rows packed, one 8B atomic
        __hip_atomic_store(
            (unsigned long long*)&hx[(((size_t)p * 64 + c) * 512 + ng) * 16 + q * 4],
            pk.u, __ATOMIC_RELAXED, __HIP_MEMORY_SCOPE_AGENT);
#pragma unroll
      for (int r = 0; r < 4; r++) {
        int b = row0 + q * 4 + r;
        out_h[((size_t)b * TSEQ + t) * 512 + ng] = pk.h4[r];
        if (out_f) out_f[((size_t)b * TSEQ + t) * 512 + ng] = hv[r];
        if (t == TSEQ - 1) hT[(size_t)b * 512 + ng] = pk.h4[r];
      }
    }
    if (t == TSEQ - 1) break;

    __builtin_amdgcn_s_waitcnt(0);  // drain coherent stores to the coherence point
    __syncthreads();
    if (tid == 0) {
      __hip_atomic_fetch_add(myctr, 1, __ATOMIC_RELAXED, __HIP_MEMORY_SCOPE_AGENT);
      int target = 4 * (t + 1);
      while (__hip_atomic_load(myctr, __ATOMIC_RELAXED, __HIP_MEMORY_SCOPE_AGENT) < target)
        __builtin_amdgcn_s_sleep(1);
    }
    __syncthreads();

    // rebuild full h_t into LDS (row-major) from col-major hx, coherent loads
    {
      unsigned long long v[8];
#pragma unroll
      for (int cc = 0; cc < 2; cc++) {
        int col = tid * 2 + cc;
        const unsigned long long* bp =
            (const unsigned long long*)&hx[(((size_t)p * 64 + c) * 512 + col) * 16];
#pragma unroll
        for (int j = 0; j < 4; j++)
          v[cc * 4 + j] = __hip_atomic_load(bp + j, __ATOMIC_RELAXED, __HIP_MEMORY_SCOPE_AGENT);
      }
#pragma unroll
      for (int cc = 0; cc < 2; cc++) {
        int col = tid * 2 + cc;
        union { unsigned long long u[4]; f16 h[16]; } un;
        un.u[0] = v[cc * 4]; un.u[1] = v[cc * 4 + 1];
        un.u[2] = v[cc * 4 + 2]; un.u[3] = v[cc * 4 + 3];
#pragma unroll
        for (int k = 0; k < 16; k++) As[k * 520 + col] = un.h[k];
      }
    }
    if (is_l0 && tid < 96)
      xs[tid / 6][tid % 6] = x[((size_t)(row0 + tid / 6) * TSEQ + (t + 1)) * 6 + tid % 6];
    __syncthreads();
  }
}

// ---------------- decoder (cluster of 4 blocks, fence-free sync) ----------------
// hstate layout: [buf 8][cluster 64][col 512][row 16] f16 (coherent access only).
__global__ __launch_bounds__(256) void k_dec_rec(
    const f16* __restrict__ Wih, const f16* __restrict__ Whh,
    const float* __restrict__ decB, const f16* __restrict__ hT,
    f16* __restrict__ hstate, f16* __restrict__ dec_out, int* __restrict__ ctr) {
  __shared__ f16 xb[16 * 520];
  __shared__ f16 hb[16 * 520];
  const int tid = threadIdx.x;
  const int w = tid >> 6, lane = tid & 63, q = lane >> 4, l15 = lane & 15;
  const int c = blockIdx.x & 63, sub = blockIdx.x >> 6;
  const int row0 = c * 16;
  const int ncol0 = sub * 128 + w * 32;
  int* myctr = ctr + c * 32;
  const size_t LSZ = (size_t)1024 * 512;

  auto load_rm = [&](f16* dst, const f16* src) {  // row-major plain (hT, prev kernel)
#pragma unroll
    for (int i = 0; i < 4; i++) {
      int idx = tid + 256 * i; int m = idx >> 6, kc = idx & 63;
      *(f16x8*)&dst[m * 520 + kc * 8] = *(const f16x8*)&src[(size_t)(row0 + m) * 512 + kc * 8];
    }
  };
  auto load_cm = [&](f16* dst, int buf) {  // col-major coherent (hstate)
    unsigned long long v[8];
#pragma unroll
    for (int cc = 0; cc < 2; cc++) {
      int col = tid * 2 + cc;
      const unsigned long long* bp =
          (const unsigned long long*)&hstate[(((size_t)buf * 64 + c) * 512 + col) * 16];
#pragma unroll
      for (int j = 0; j < 4; j++)
        v[cc * 4 + j] = __hip_atomic_load(bp + j, __ATOMIC_RELAXED, __HIP_MEMORY_SCOPE_AGENT);
    }
#pragma unroll
    for (int cc = 0; cc < 2; cc++) {
      int col = tid * 2 + cc;
      union { unsigned long long u[4]; f16 h[16]; } un;
      un.u[0] = v[cc * 4]; un.u[1] = v[cc * 4 + 1];
      un.u[2] = v[cc * 4 + 2]; un.u[3] = v[cc * 4 + 3];
#pragma unroll
      for (int k = 0; k < 16; k++) dst[k * 520 + col] = un.h[k];
    }
  };

  for (int s = 0; s < PRED; s++) {
    int wb = (s + 1) & 1, rb = s & 1;
    for (int l = 0; l < 4; l++) {
      if (l == 0) {
        if (s == 0) load_rm(xb, hT + 3 * LSZ);
        else load_cm(xb, rb * 4 + 3);
      } else {
        load_cm(xb, wb * 4 + (l - 1));
      }
      if (s == 0) load_rm(hb, hT + (size_t)l * LSZ);
      else load_cm(hb, rb * 4 + l);
      __syncthreads();

      const f32x4 zero = {0.f, 0.f, 0.f, 0.f};
      f32x4 acc0 = zero, acc1 = zero;
      const f16* Wl = Wih + (size_t)l * 512 * 512;
      const f16* Ul = Whh + (size_t)l * 512 * 512;
      int ng0 = ncol0 + l15, ng1 = ncol0 + 16 + l15;
#pragma unroll
      for (int kk = 0; kk < 16; kk++) {
        f16x8 a = *(const f16x8*)&xb[l15 * 520 + kk * 32 + q * 8];
        f16x8 bv0 = *(const f16x8*)&Wl[(size_t)ng0 * 512 + kk * 32 + q * 8];
        f16x8 bv1 = *(const f16x8*)&Wl[(size_t)ng1 * 512 + kk * 32 + q * 8];
        acc0 = __builtin_amdgcn_mfma_f32_16x16x32_f16(a, bv0, acc0, 0, 0, 0);
        acc1 = __builtin_amdgcn_mfma_f32_16x16x32_f16(a, bv1, acc1, 0, 0, 0);
      }
#pragma unroll
      for (int kk = 0; kk < 16; kk++) {
        f16x8 a = *(const f16x8*)&hb[l15 * 520 + kk * 32 + q * 8];
        f16x8 bv0 = *(const f16x8*)&Ul[(size_t)ng0 * 512 + kk * 32 + q * 8];
        f16x8 bv1 = *(const f16x8*)&Ul[(size_t)ng1 * 512 + kk * 32 + q * 8];
        acc0 = __builtin_amdgcn_mfma_f32_16x16x32_f16(a, bv0, acc0, 0, 0, 0);
        acc1 = __builtin_amdgcn_mfma_f32_16x16x32_f16(a, bv1, acc1, 0, 0, 0);
      }

      int obuf = wb * 4 + l;
#pragma unroll
      for (int t2 = 0; t2 < 2; t2++) {
        f32x4 accv = t2 ? acc1 : acc0;
        int ng = ncol0 + t2 * 16 + l15;
        union { unsigned long long u; f16 h4[4]; } pk;
#pragma unroll
        for (int r = 0; r < 4; r++)
          pk.h4[r] = (f16)tanhf(accv[r] + decB[l * 512 + ng]);
        __hip_atomic_store(
            (unsigned long long*)&hstate[(((size_t)obuf * 64 + c) * 512 + ng) * 16 + q * 4],
            pk.u, __ATOMIC_RELAXED, __HIP_MEMORY_SCOPE_AGENT);
        if (l == 3) {
#pragma unroll
          for (int r = 0; r < 4; r++)
            dec_out[((size_t)(row0 + q * 4 + r) * PRED + s) * 512 + ng] = pk.h4[r];
        }
      }
      __builtin_amdgcn_s_waitcnt(0);
      __syncthreads();
      if (tid == 0) {
        __hip_atomic_fetch_add(myctr, 1, __ATOMIC_RELAXED, __HIP_MEMORY_SCOPE_AGENT);
        int target = 4 * (s * 4 + l + 1);
        while (__hip_atomic_load(myctr, __ATOMIC_RELAXED, __HIP_MEMORY_SCOPE_AGENT) < target)
          __builtin_amdgcn_s_sleep(1);
      }
      __syncthreads();
    }
  }
}

// ---------------- final FC ----------------
__global__ __launch_bounds__(256) void k_fc(
    const f16* __restrict__ dec_out, const float* __restrict__ fcW,
    const float* __restrict__ fcb, float* __restrict__ out) {
  __shared__ float Wl[6 * 512];
  __shared__ float bl[8];
  int tid = threadIdx.x;
  for (int i = tid; i < 3072; i += 256) Wl[i] = fcW[i];
  if (tid < 6) bl[tid] = fcb[tid];
  __syncthreads();
  int g = blockIdx.x * 256 + tid;  // 0..10239
  const f16* row = dec_out + (size_t)g * 512;
  float acc[6] = {0, 0, 0, 0, 0, 0};
  for (int kc = 0; kc < 64; kc++) {
    f16x8 xv = *(const f16x8*)&row[kc * 8];
#pragma unroll
    for (int j = 0; j < 8; j++) {
      float xf = (float)xv[j];
#pragma unroll
      for (int o = 0; o < 6; o++) acc[o] += xf * Wl[o * 512 + kc * 8 + j];
    }
  }
#pragma unroll
  for (int o = 0; o < 6; o++) out[(size_t)g * 6 + o] = acc[o] + bl[o];
}

extern "C" void kernel_launch(void* const* d_in, const int* in_sizes, int n_in,
                              void* d_out, int out_size, void* d_ws, size_t ws_size,
                              hipStream_t stream) {
  const float* x      = (const float*)d_in[0];
  const float* Wih0   = (const float*)d_in[1];
  const float* eWih32 = (const float*)d_in[2];
  const float* eWhh32 = (const float*)d_in[3];
  const float* ebih   = (const float*)d_in[4];
  const float* ebhh   = (const float*)d_in[5];
  const float* dWih32 = (const float*)d_in[6];
  const float* dWhh32 = (const float*)d_in[7];
  const float* dbih   = (const float*)d_in[8];
  const float* dbhh   = (const float*)d_in[9];
  const float* fcW    = (const float*)d_in[10];
  const float* fcb    = (const float*)d_in[11];
  float* outp = (float*)d_out;

  char* ws = (char*)d_ws;
  size_t off = 0;
  auto alloc = [&](size_t bytes) { void* p = ws + off; off += (bytes + 255) & ~255ULL; return p; };
  f16* outA   = (f16*)alloc((size_t)131072 * 512 * 2);
  f16* xwB    = (f16*)alloc((size_t)131072 * 512 * 2);
  f16* eWih   = (f16*)alloc((size_t)3 * 262144 * 2);
  f16* eWhh   = (f16*)alloc((size_t)4 * 262144 * 2);
  f16* dWih   = (f16*)alloc((size_t)4 * 262144 * 2);
  f16* dWhh   = (f16*)alloc((size_t)4 * 262144 * 2);
  float* encB = (float*)alloc(2048 * 4);
  float* decB = (float*)alloc(2048 * 4);
  f16* hT     = (f16*)alloc((size_t)4 * 1024 * 512 * 2);
  f16* hstate = (f16*)alloc((size_t)8 * 1024 * 512 * 2);
  f16* hx     = (f16*)alloc((size_t)2 * 1024 * 512 * 2);
  f16* dec_o  = (f16*)alloc((size_t)1024 * 10 * 512 * 2);
  int* ctr    = (int*)alloc(5 * 64 * 32 * 4);

  hipMemsetAsync(ctr, 0, 5 * 64 * 32 * 4, stream);
  k_cvt<<<512, 256, 0, stream>>>(eWih32, eWih, 3 * 262144);
  k_cvt<<<512, 256, 0, stream>>>(eWhh32, eWhh, 4 * 262144);
  k_cvt<<<512, 256, 0, stream>>>(dWih32, dWih, 4 * 262144);
  k_cvt<<<512, 256, 0, stream>>>(dWhh32, dWhh, 4 * 262144);
  k_bias<<<8, 256, 0, stream>>>(ebih, ebhh, encB, 2048);
  k_bias<<<8, 256, 0, stream>>>(dbih, dbhh, decB, 2048);

  // encoder layer 0 (input transform K=6 fused)
  k_enc_rec<<<256, 256, 0, stream>>>(nullptr, x, Wih0, encB, eWhh, outA, nullptr, hT, hx, ctr, 1);
  for (int l = 1; l < 4; l++) {
    k_gemm_xw<<<dim3(1024, 2), 256, 0, stream>>>(outA, eWih + (size_t)(l - 1) * 262144,
                                                 encB + l * 512, xwB);
    float* of = (l == 3) ? outp : nullptr;
    k_enc_rec<<<256, 256, 0, stream>>>(xwB, nullptr, nullptr, nullptr,
                                       eWhh + (size_t)l * 262144, outA, of,
                                       hT + (size_t)l * 524288, hx, ctr + l * 2048, 0);
  }
  k_dec_rec<<<256, 256, 0, stream>>>(dWih, dWhh, decB, hT, hstate, dec_o, ctr + 4 * 2048);
  k_fc<<<40, 256, 0, stream>>>(dec_o, fcW, fcb, outp + (size_t)1024 * 128 * 512);
}

// Round 3
// 3156.043 us; speedup vs baseline: 3.7284x; 1.0882x over previous
//
#include <hip/hip_runtime.h>

typedef _Float16 f16;
typedef _Float16 f16x8 __attribute__((ext_vector_type(8)));
typedef float    f32x4 __attribute__((ext_vector_type(4)));
typedef unsigned long long u64;

#define TSEQ 128
#define PRED 10

// ---------------- small utility kernels ----------------
__global__ void k_cvt(const float* __restrict__ src, f16* __restrict__ dst, int n) {
  int i = blockIdx.x * blockDim.x + threadIdx.x;
  int stride = gridDim.x * blockDim.x;
  for (; i < n; i += stride) dst[i] = (f16)src[i];
}

__global__ void k_bias(const float* __restrict__ a, const float* __restrict__ b,
                       float* __restrict__ o, int n) {
  int i = blockIdx.x * blockDim.x + threadIdx.x;
  if (i < n) o[i] = a[i] + b[i];
}

// ---------------- input-transform GEMM ----------------
__global__ __launch_bounds__(256) void k_gemm_xw(
    const f16* __restrict__ A, const f16* __restrict__ W,
    const float* __restrict__ bias, f16* __restrict__ C) {
  __shared__ f16 As[128 * 72];
  __shared__ f16 Bs[256 * 72];
  const int tid = threadIdx.x;
  const int w = tid >> 6, lane = tid & 63;
  const int wm = w >> 1, wn = w & 1;
  const int q = lane >> 4, l15 = lane & 15;
  const int m0 = blockIdx.x * 128;
  const int n0 = blockIdx.y * 256;

  f32x4 acc[4][8];
  const f32x4 zero = {0.f, 0.f, 0.f, 0.f};
#pragma unroll
  for (int i = 0; i < 4; i++)
#pragma unroll
    for (int j = 0; j < 8; j++) acc[i][j] = zero;

  for (int k0 = 0; k0 < 512; k0 += 64) {
    __syncthreads();
#pragma unroll
    for (int i = 0; i < 4; i++) {
      int ch = tid + 256 * i; int r = ch >> 3, kc = ch & 7;
      *(f16x8*)&As[r * 72 + kc * 8] = *(const f16x8*)&A[(size_t)(m0 + r) * 512 + k0 + kc * 8];
    }
#pragma unroll
    for (int i = 0; i < 8; i++) {
      int ch = tid + 256 * i; int r = ch >> 3, kc = ch & 7;
      *(f16x8*)&Bs[r * 72 + kc * 8] = *(const f16x8*)&W[(size_t)(n0 + r) * 512 + k0 + kc * 8];
    }
    __syncthreads();
#pragma unroll
    for (int kk = 0; kk < 2; kk++) {
      f16x8 af[4], bf[8];
#pragma unroll
      for (int mt = 0; mt < 4; mt++)
        af[mt] = *(const f16x8*)&As[(wm * 64 + mt * 16 + l15) * 72 + kk * 32 + q * 8];
#pragma unroll
      for (int nt = 0; nt < 8; nt++)
        bf[nt] = *(const f16x8*)&Bs[(wn * 128 + nt * 16 + l15) * 72 + kk * 32 + q * 8];
#pragma unroll
      for (int mt = 0; mt < 4; mt++)
#pragma unroll
        for (int nt = 0; nt < 8; nt++)
          acc[mt][nt] = __builtin_amdgcn_mfma_f32_16x16x32_f16(af[mt], bf[nt], acc[mt][nt], 0, 0, 0);
    }
  }
#pragma unroll
  for (int mt = 0; mt < 4; mt++)
#pragma unroll
    for (int nt = 0; nt < 8; nt++)
#pragma unroll
      for (int r = 0; r < 4; r++) {
        int mg = m0 + wm * 64 + mt * 16 + q * 4 + r;
        int ng = n0 + wn * 128 + nt * 16 + l15;
        C[(size_t)mg * 512 + ng] = (f16)(acc[mt][nt][r] + bias[ng]);
      }
}

// ---------------- encoder recurrence (cluster of 4 blocks, fence-free sync) ----
__global__ __launch_bounds__(256) void k_enc_rec(
    const f16* __restrict__ xw, const float* __restrict__ x,
    const float* __restrict__ Wih0, const float* __restrict__ bias0,
    const f16* __restrict__ Whh, f16* __restrict__ out_h,
    float* __restrict__ out_f, f16* __restrict__ hT,
    f16* __restrict__ hx, int* __restrict__ ctr, int is_l0) {
  __shared__ f16 As[16 * 520];
  __shared__ float xs[16][8];
  const int tid = threadIdx.x;
  const int w = tid >> 6, lane = tid & 63, q = lane >> 4, l15 = lane & 15;
  const int c = blockIdx.x & 63, sub = blockIdx.x >> 6;
  const int row0 = c * 16;
  const int ncol0 = sub * 128 + w * 32;
  int* myctr = ctr + c * 32;

  // register-resident B fragments of Whh for this block's 128 cols
  f16x8 Bfr[2][16];
#pragma unroll
  for (int t2 = 0; t2 < 2; t2++) {
    int ng = ncol0 + t2 * 16 + l15;
#pragma unroll
    for (int kk = 0; kk < 16; kk++)
      Bfr[t2][kk] = *(const f16x8*)&Whh[(size_t)ng * 512 + kk * 32 + q * 8];
  }

  float w0[2][6]; float b0[2];
  if (is_l0) {
#pragma unroll
    for (int t2 = 0; t2 < 2; t2++) {
      int ng = ncol0 + t2 * 16 + l15;
#pragma unroll
      for (int d = 0; d < 6; d++) w0[t2][d] = Wih0[ng * 6 + d];
      b0[t2] = bias0[ng];
    }
  }

  for (int i = tid; i < 16 * 520; i += 256) As[i] = (f16)0.0f;
  if (is_l0 && tid < 96) xs[tid / 6][tid % 6] = x[(size_t)(row0 + tid / 6) * TSEQ * 6 + tid % 6];
  __syncthreads();

  for (int t = 0; t < TSEQ; t++) {
    const int p = t & 1;
    // hoist xw loads (latency hidden under MFMA)
    f16 xwr[2][4];
    if (!is_l0) {
#pragma unroll
      for (int t2 = 0; t2 < 2; t2++)
#pragma unroll
        for (int r = 0; r < 4; r++)
          xwr[t2][r] = xw[((size_t)(row0 + q * 4 + r) * TSEQ + t) * 512 + ncol0 + t2 * 16 + l15];
    }

    const f32x4 zero = {0.f, 0.f, 0.f, 0.f};
    f32x4 acc0 = zero, acc1 = zero;
#pragma unroll
    for (int kk = 0; kk < 16; kk++) {
      f16x8 a = *(const f16x8*)&As[l15 * 520 + kk * 32 + q * 8];
      acc0 = __builtin_amdgcn_mfma_f32_16x16x32_f16(a, Bfr[0][kk], acc0, 0, 0, 0);
      acc1 = __builtin_amdgcn_mfma_f32_16x16x32_f16(a, Bfr[1][kk], acc1, 0, 0, 0);
    }

    float hv[2][4];
    union { u64 u; f16 h4[4]; } pk[2];
#pragma unroll
    for (int t2 = 0; t2 < 2; t2++) {
      f32x4 accv = t2 ? acc1 : acc0;
#pragma unroll
      for (int r = 0; r < 4; r++) {
        int m = q * 4 + r;
        float pre;
        if (is_l0) {
          float xwv = b0[t2];
#pragma unroll
          for (int d = 0; d < 6; d++) xwv += xs[m][d] * w0[t2][d];
          pre = accv[r] + xwv;
        } else {
          pre = accv[r] + (float)xwr[t2][r];
        }
        hv[t2][r] = tanhf(pre);
        pk[t2].h4[r] = (f16)hv[t2][r];
      }
    }

    if (t < TSEQ - 1) {
      // only the exchange stores sit before the drain+arrive
#pragma unroll
      for (int t2 = 0; t2 < 2; t2++) {
        int ng = ncol0 + t2 * 16 + l15;
        __hip_atomic_store(
            (u64*)&hx[(((size_t)p * 64 + c) * 512 + ng) * 16 + q * 4],
            pk[t2].u, __ATOMIC_RELAXED, __HIP_MEMORY_SCOPE_AGENT);
      }
      __builtin_amdgcn_s_waitcnt(0);
      __syncthreads();
      if (tid == 0)
        __hip_atomic_fetch_add(myctr, 1, __ATOMIC_RELAXED, __HIP_MEMORY_SCOPE_AGENT);
    }

    // bulk output stores overlap barrier propagation
#pragma unroll
    for (int t2 = 0; t2 < 2; t2++) {
      int ng = ncol0 + t2 * 16 + l15;
#pragma unroll
      for (int r = 0; r < 4; r++) {
        int b = row0 + q * 4 + r;
        out_h[((size_t)b * TSEQ + t) * 512 + ng] = pk[t2].h4[r];
        if (out_f) out_f[((size_t)b * TSEQ + t) * 512 + ng] = hv[t2][r];
        if (t == TSEQ - 1) hT[(size_t)b * 512 + ng] = pk[t2].h4[r];
      }
    }
    if (t == TSEQ - 1) break;

    if (tid == 0) {
      int target = 4 * (t + 1);
      while (__hip_atomic_load(myctr, __ATOMIC_RELAXED, __HIP_MEMORY_SCOPE_AGENT) < target)
        __builtin_amdgcn_s_sleep(1);
    }
    __syncthreads();

    // rebuild h_t into LDS from col-major hx; b32-packed LDS writes
    {
      u64 v[8];
#pragma unroll
      for (int cc = 0; cc < 2; cc++) {
        int col = tid * 2 + cc;
        const u64* bp = (const u64*)&hx[(((size_t)p * 64 + c) * 512 + col) * 16];
#pragma unroll
        for (int j = 0; j < 4; j++)
          v[cc * 4 + j] = __hip_atomic_load(bp + j, __ATOMIC_RELAXED, __HIP_MEMORY_SCOPE_AGENT);
      }
      union { u64 u[4]; f16 h[16]; } un0, un1;
      un0.u[0] = v[0]; un0.u[1] = v[1]; un0.u[2] = v[2]; un0.u[3] = v[3];
      un1.u[0] = v[4]; un1.u[1] = v[5]; un1.u[2] = v[6]; un1.u[3] = v[7];
#pragma unroll
      for (int k = 0; k < 16; k++) {
        union { f16 h2[2]; unsigned int u; } pw;
        pw.h2[0] = un0.h[k]; pw.h2[1] = un1.h[k];
        *(unsigned int*)&As[k * 520 + tid * 2] = pw.u;
      }
    }
    if (is_l0 && tid < 96)
      xs[tid / 6][tid % 6] = x[((size_t)(row0 + tid / 6) * TSEQ + (t + 1)) * 6 + tid % 6];
    __syncthreads();
  }
}

// ---------------- decoder (cluster of 4 blocks, fence-free sync) ----------------
// XCD-aware mapping: c = blockIdx>>2, sub = blockIdx&3 — under round-robin
// dispatch each XCD sees a single col-sub, so the 1 MB weight slice stays
// L2-resident across all 40 cells.
__global__ __launch_bounds__(256) void k_dec_rec(
    const f16* __restrict__ Wih, const f16* __restrict__ Whh,
    const float* __restrict__ decB, const f16* __restrict__ hT,
    f16* __restrict__ hstate, f16* __restrict__ dec_out, int* __restrict__ ctr) {
  __shared__ f16 xb[16 * 520];
  __shared__ f16 hb[16 * 520];
  const int tid = threadIdx.x;
  const int w = tid >> 6, lane = tid & 63, q = lane >> 4, l15 = lane & 15;
  const int c = blockIdx.x >> 2, sub = blockIdx.x & 3;
  const int row0 = c * 16;
  const int ncol0 = sub * 128 + w * 32;
  int* myctr = ctr + c * 32;
  const size_t LSZ = (size_t)1024 * 512;

  auto load_rm = [&](f16* dst, const f16* src) {  // row-major plain (hT)
#pragma unroll
    for (int i = 0; i < 4; i++) {
      int idx = tid + 256 * i; int m = idx >> 6, kc = idx & 63;
      *(f16x8*)&dst[m * 520 + kc * 8] = *(const f16x8*)&src[(size_t)(row0 + m) * 512 + kc * 8];
    }
  };
  auto load_cm = [&](f16* dst, int buf) {  // col-major coherent (hstate)
    u64 v[8];
#pragma unroll
    for (int cc = 0; cc < 2; cc++) {
      int col = tid * 2 + cc;
      const u64* bp = (const u64*)&hstate[(((size_t)buf * 64 + c) * 512 + col) * 16];
#pragma unroll
      for (int j = 0; j < 4; j++)
        v[cc * 4 + j] = __hip_atomic_load(bp + j, __ATOMIC_RELAXED, __HIP_MEMORY_SCOPE_AGENT);
    }
    union { u64 u[4]; f16 h[16]; } un0, un1;
    un0.u[0] = v[0]; un0.u[1] = v[1]; un0.u[2] = v[2]; un0.u[3] = v[3];
    un1.u[0] = v[4]; un1.u[1] = v[5]; un1.u[2] = v[6]; un1.u[3] = v[7];
#pragma unroll
    for (int k = 0; k < 16; k++) {
      union { f16 h2[2]; unsigned int u; } pw;
      pw.h2[0] = un0.h[k]; pw.h2[1] = un1.h[k];
      *(unsigned int*)&dst[k * 520 + tid * 2] = pw.u;
    }
  };

  for (int s = 0; s < PRED; s++) {
    int wb = (s + 1) & 1, rb = s & 1;
    for (int l = 0; l < 4; l++) {
      const bool last = (s == PRED - 1) && (l == 3);
      if (l == 0) {
        if (s == 0) load_rm(xb, hT + 3 * LSZ);
        else load_cm(xb, rb * 4 + 3);
      } else {
        load_cm(xb, wb * 4 + (l - 1));
      }
      if (s == 0) load_rm(hb, hT + (size_t)l * LSZ);
      else load_cm(hb, rb * 4 + l);
      __syncthreads();

      const f32x4 zero = {0.f, 0.f, 0.f, 0.f};
      f32x4 acc0 = zero, acc1 = zero;
      const f16* Wl = Wih + (size_t)l * 512 * 512;
      const f16* Ul = Whh + (size_t)l * 512 * 512;
      int ng0 = ncol0 + l15, ng1 = ncol0 + 16 + l15;
#pragma unroll
      for (int kk = 0; kk < 16; kk++) {
        f16x8 a = *(const f16x8*)&xb[l15 * 520 + kk * 32 + q * 8];
        f16x8 bv0 = *(const f16x8*)&Wl[(size_t)ng0 * 512 + kk * 32 + q * 8];
        f16x8 bv1 = *(const f16x8*)&Wl[(size_t)ng1 * 512 + kk * 32 + q * 8];
        acc0 = __builtin_amdgcn_mfma_f32_16x16x32_f16(a, bv0, acc0, 0, 0, 0);
        acc1 = __builtin_amdgcn_mfma_f32_16x16x32_f16(a, bv1, acc1, 0, 0, 0);
      }
#pragma unroll
      for (int kk = 0; kk < 16; kk++) {
        f16x8 a = *(const f16x8*)&hb[l15 * 520 + kk * 32 + q * 8];
        f16x8 bv0 = *(const f16x8*)&Ul[(size_t)ng0 * 512 + kk * 32 + q * 8];
        f16x8 bv1 = *(const f16x8*)&Ul[(size_t)ng1 * 512 + kk * 32 + q * 8];
        acc0 = __builtin_amdgcn_mfma_f32_16x16x32_f16(a, bv0, acc0, 0, 0, 0);
        acc1 = __builtin_amdgcn_mfma_f32_16x16x32_f16(a, bv1, acc1, 0, 0, 0);
      }

      int obuf = wb * 4 + l;
      union { u64 u; f16 h4[4]; } pk[2];
#pragma unroll
      for (int t2 = 0; t2 < 2; t2++) {
        f32x4 accv = t2 ? acc1 : acc0;
        int ng = ncol0 + t2 * 16 + l15;
#pragma unroll
        for (int r = 0; r < 4; r++)
          pk[t2].h4[r] = (f16)tanhf(accv[r] + decB[l * 512 + ng]);
      }

      if (!last) {
#pragma unroll
        for (int t2 = 0; t2 < 2; t2++) {
          int ng = ncol0 + t2 * 16 + l15;
          __hip_atomic_store(
              (u64*)&hstate[(((size_t)obuf * 64 + c) * 512 + ng) * 16 + q * 4],
              pk[t2].u, __ATOMIC_RELAXED, __HIP_MEMORY_SCOPE_AGENT);
        }
        __builtin_amdgcn_s_waitcnt(0);
        __syncthreads();
        if (tid == 0)
          __hip_atomic_fetch_add(myctr, 1, __ATOMIC_RELAXED, __HIP_MEMORY_SCOPE_AGENT);
      }

      if (l == 3) {  // bulk output overlaps barrier propagation
#pragma unroll
        for (int t2 = 0; t2 < 2; t2++) {
          int ng = ncol0 + t2 * 16 + l15;
#pragma unroll
          for (int r = 0; r < 4; r++)
            dec_out[((size_t)(row0 + q * 4 + r) * PRED + s) * 512 + ng] = pk[t2].h4[r];
        }
      }

      if (!last) {
        if (tid == 0) {
          int target = 4 * (s * 4 + l + 1);
          while (__hip_atomic_load(myctr, __ATOMIC_RELAXED, __HIP_MEMORY_SCOPE_AGENT) < target)
            __builtin_amdgcn_s_sleep(1);
        }
        __syncthreads();
      }
    }
  }
}

// ---------------- final FC ----------------
__global__ __launch_bounds__(256) void k_fc(
    const f16* __restrict__ dec_out, const float* __restrict__ fcW,
    const float* __restrict__ fcb, float* __restrict__ out) {
  __shared__ float Wl[6 * 512];
  __shared__ float bl[8];
  int tid = threadIdx.x;
  for (int i = tid; i < 3072; i += 256) Wl[i] = fcW[i];
  if (tid < 6) bl[tid] = fcb[tid];
  __syncthreads();
  int g = blockIdx.x * 256 + tid;  // 0..10239
  const f16* row = dec_out + (size_t)g * 512;
  float acc[6] = {0, 0, 0, 0, 0, 0};
  for (int kc = 0; kc < 64; kc++) {
    f16x8 xv = *(const f16x8*)&row[kc * 8];
#pragma unroll
    for (int j = 0; j < 8; j++) {
      float xf = (float)xv[j];
#pragma unroll
      for (int o = 0; o < 6; o++) acc[o] += xf * Wl[o * 512 + kc * 8 + j];
    }
  }
#pragma unroll
  for (int o = 0; o < 6; o++) out[(size_t)g * 6 + o] = acc[o] + bl[o];
}

extern "C" void kernel_launch(void* const* d_in, const int* in_sizes, int n_in,
                              void* d_out, int out_size, void* d_ws, size_t ws_size,
                              hipStream_t stream) {
  const float* x      = (const float*)d_in[0];
  const float* Wih0   = (const float*)d_in[1];
  const float* eWih32 = (const float*)d_in[2];
  const float* eWhh32 = (const float*)d_in[3];
  const float* ebih   = (const float*)d_in[4];
  const float* ebhh   = (const float*)d_in[5];
  const float* dWih32 = (const float*)d_in[6];
  const float* dWhh32 = (const float*)d_in[7];
  const float* dbih   = (const float*)d_in[8];
  const float* dbhh   = (const float*)d_in[9];
  const float* fcW    = (const float*)d_in[10];
  const float* fcb    = (const float*)d_in[11];
  float* outp = (float*)d_out;

  char* ws = (char*)d_ws;
  size_t off = 0;
  auto alloc = [&](size_t bytes) { void* p = ws + off; off += (bytes + 255) & ~255ULL; return p; };
  f16* outA   = (f16*)alloc((size_t)131072 * 512 * 2);
  f16* xwB    = (f16*)alloc((size_t)131072 * 512 * 2);
  f16* eWih   = (f16*)alloc((size_t)3 * 262144 * 2);
  f16* eWhh   = (f16*)alloc((size_t)4 * 262144 * 2);
  f16* dWih   = (f16*)alloc((size_t)4 * 262144 * 2);
  f16* dWhh   = (f16*)alloc((size_t)4 * 262144 * 2);
  float* encB = (float*)alloc(2048 * 4);
  float* decB = (float*)alloc(2048 * 4);
  f16* hT     = (f16*)alloc((size_t)4 * 1024 * 512 * 2);
  f16* hstate = (f16*)alloc((size_t)8 * 1024 * 512 * 2);
  f16* hx     = (f16*)alloc((size_t)2 * 1024 * 512 * 2);
  f16* dec_o  = (f16*)alloc((size_t)1024 * 10 * 512 * 2);
  int* ctr    = (int*)alloc(5 * 64 * 32 * 4);

  hipMemsetAsync(ctr, 0, 5 * 64 * 32 * 4, stream);
  k_cvt<<<512, 256, 0, stream>>>(eWih32, eWih, 3 * 262144);
  k_cvt<<<512, 256, 0, stream>>>(eWhh32, eWhh, 4 * 262144);
  k_cvt<<<512, 256, 0, stream>>>(dWih32, dWih, 4 * 262144);
  k_cvt<<<512, 256, 0, stream>>>(dWhh32, dWhh, 4 * 262144);
  k_bias<<<8, 256, 0, stream>>>(ebih, ebhh, encB, 2048);
  k_bias<<<8, 256, 0, stream>>>(dbih, dbhh, decB, 2048);

  // encoder layer 0 (input transform K=6 fused)
  k_enc_rec<<<256, 256, 0, stream>>>(nullptr, x, Wih0, encB, eWhh, outA, nullptr, hT, hx, ctr, 1);
  for (int l = 1; l < 4; l++) {
    k_gemm_xw<<<dim3(1024, 2), 256, 0, stream>>>(outA, eWih + (size_t)(l - 1) * 262144,
                                                 encB + l * 512, xwB);
    float* of = (l == 3) ? outp : nullptr;
    k_enc_rec<<<256, 256, 0, stream>>>(xwB, nullptr, nullptr, nullptr,
                                       eWhh + (size_t)l * 262144, outA, of,
                                       hT + (size_t)l * 524288, hx, ctr + l * 2048, 0);
  }
  k_dec_rec<<<256, 256, 0, stream>>>(dWih, dWhh, decB, hT, hstate, dec_o, ctr + 4 * 2048);
  k_fc<<<40, 256, 0, stream>>>(dec_o, fcW, fcb, outp + (size_t)1024 * 128 * 512);
}